// Round 3
// baseline (1183.893 us; speedup 1.0000x reference)
//
#include <hip/hip_runtime.h>

#define DEVFN __device__ __forceinline__

typedef float  floatx4 __attribute__((ext_vector_type(4)));
typedef __bf16 bf16x8  __attribute__((ext_vector_type(8)));

#define MFMA16(a, b, c) __builtin_amdgcn_mfma_f32_16x16x32_bf16((a), (b), (c), 0, 0, 0)

DEVFN unsigned short f2bf(float f) {
  union { float f; unsigned u; } v; v.f = f;
  unsigned r = v.u + 0x7FFFu + ((v.u >> 16) & 1u);
  return (unsigned short)(r >> 16);
}
DEVFN float bf2f(unsigned short b) {
  union { unsigned u; float f; } v; v.u = ((unsigned)b) << 16;
  return v.f;
}
DEVFN void async16(void* lds, const void* g) {
  __builtin_amdgcn_global_load_lds(
      (const __attribute__((address_space(1))) unsigned int*)g,
      (__attribute__((address_space(3))) unsigned int*)lds, 16, 0, 0);
}
DEVFN bf16x8 ld8(const unsigned short* p) { return *(const bf16x8*)p; }

// XCD swizzle: linear block id -> (n_tile, m_tile) such that each XCD
// (id % 8 round-robin) covers a compact 4n x 16m rectangle: per-XCD per-kstep
// working set 4n*weights + 16m*x instead of 2n + 32m (1.5x less L2-fill).
DEVFN void swizzle_nm(int id, int& n0, int& m0) {
  int xg = id & 7, tg = id >> 3;
  n0 = ((xg & 3) * 4 + (tg & 3)) * 128;
  m0 = ((xg >> 2) * 16 + (tg >> 2)) * 128;
}

// ---------------------------------------------------------------------------
// split fp32 -> bf16 hi (+ optional lo residual)
// ---------------------------------------------------------------------------
__global__ __launch_bounds__(256) void split_kernel(
    const float4* __restrict__ x, ushort4* __restrict__ hi,
    ushort4* __restrict__ lo, int n4) {
  int i = blockIdx.x * 256 + threadIdx.x;
  if (i >= n4) return;
  float4 v = x[i];
  ushort4 h;
  h.x = f2bf(v.x); h.y = f2bf(v.y); h.z = f2bf(v.z); h.w = f2bf(v.w);
  hi[i] = h;
  if (lo) {
    ushort4 l;
    l.x = f2bf(v.x - bf2f(h.x)); l.y = f2bf(v.y - bf2f(h.y));
    l.z = f2bf(v.z - bf2f(h.z)); l.w = f2bf(v.w - bf2f(h.w));
    lo[i] = l;
  }
}

// ---------------------------------------------------------------------------
// RoPE tables in fp64 (T=2048, d2=64)
// ---------------------------------------------------------------------------
__global__ __launch_bounds__(256) void rope_tables(float* __restrict__ cosT,
                                                   float* __restrict__ sinT) {
  int i = blockIdx.x * 256 + threadIdx.x;
  if (i >= 2048 * 64) return;
  int t = i >> 6, d = i & 63;
  double theta = exp(-((double)(2 * d) / 128.0) * log(10000.0));
  double ang = (double)t * theta;
  cosT[i] = (float)cos(ang);
  sinT[i] = (float)sin(ang);
}

// ---------------------------------------------------------------------------
// Fused Q+K projection, flatmm-style: NO LDS staging, NO barriers in K-loop.
// All A/B fragments loaded directly global->VGPR (16 B/lane, full 64-B
// sectors); compiler pipelines with fine-grained vmcnt(N) since no s_barrier
// ever forces vmcnt(0). B rows shared 4x/wave-group via L1.
// 3-pass split bf16 for both Q and K (hi*hi + lo*hi + hi*lo).
// Epilogue: RoPE + sqk*escale + split, staged per-wave through LDS so global
// stores are contiguous 16 B/lane (kills the 4.8x write amplification).
// ---------------------------------------------------------------------------
__global__ __launch_bounds__(256, 2) void gemm_qk_flat(
    const unsigned short* __restrict__ xhi, const unsigned short* __restrict__ xlo,
    const unsigned short* __restrict__ wqh, const unsigned short* __restrict__ wql,
    const unsigned short* __restrict__ wkh, const unsigned short* __restrict__ wkl,
    const float* __restrict__ cosT, const float* __restrict__ sinT,
    const float* __restrict__ sqk,
    unsigned short* __restrict__ qhi, unsigned short* __restrict__ qlo,
    unsigned short* __restrict__ khi, unsigned short* __restrict__ klo) {
  constexpr int Kd = 2048;
  int n0, m0;
  swizzle_nm(blockIdx.x, n0, m0);
  const int tid = threadIdx.x, w = tid >> 6, lane = tid & 63;
  const int quad = lane >> 4, l16 = lane & 15;

  // per-wave epilogue staging: 16 rows x 136 shorts (272 B, 16-B aligned rows)
  __shared__ __align__(16) unsigned short stage[4][2][16 * 136];

  floatx4 accQ[2][8], accK[2][8];
#pragma unroll
  for (int i = 0; i < 2; i++)
#pragma unroll
    for (int j = 0; j < 8; j++) {
      accQ[i][j] = (floatx4){0.f, 0.f, 0.f, 0.f};
      accK[i][j] = (floatx4){0.f, 0.f, 0.f, 0.f};
    }

  const int t0 = 2 * w, t1 = 2 * w + 1;
  const size_t ra0 = (size_t)(m0 + t0 * 16 + l16) * Kd + quad * 8;
  const size_t ra1 = (size_t)(m0 + t1 * 16 + l16) * Kd + quad * 8;
  size_t rb[8];
#pragma unroll
  for (int j = 0; j < 8; j++)
    rb[j] = (size_t)(n0 + j * 16 + l16) * Kd + quad * 8;

  for (int k0 = 0; k0 < Kd; k0 += 32) {
    bf16x8 ah0 = ld8(xhi + ra0 + k0);
    bf16x8 ah1 = ld8(xhi + ra1 + k0);
    bf16x8 al0 = ld8(xlo + ra0 + k0);
    bf16x8 al1 = ld8(xlo + ra1 + k0);
#pragma unroll
    for (int j = 0; j < 8; j++) {
      bf16x8 bh = ld8(wqh + rb[j] + k0);
      bf16x8 bl = ld8(wql + rb[j] + k0);
      accQ[0][j] = MFMA16(ah0, bh, accQ[0][j]);
      accQ[1][j] = MFMA16(ah1, bh, accQ[1][j]);
      accQ[0][j] = MFMA16(al0, bh, accQ[0][j]);
      accQ[1][j] = MFMA16(al1, bh, accQ[1][j]);
      accQ[0][j] = MFMA16(ah0, bl, accQ[0][j]);
      accQ[1][j] = MFMA16(ah1, bl, accQ[1][j]);
      bh = ld8(wkh + rb[j] + k0);
      bl = ld8(wkl + rb[j] + k0);
      accK[0][j] = MFMA16(ah0, bh, accK[0][j]);
      accK[1][j] = MFMA16(ah1, bh, accK[1][j]);
      accK[0][j] = MFMA16(al0, bh, accK[0][j]);
      accK[1][j] = MFMA16(al1, bh, accK[1][j]);
      accK[0][j] = MFMA16(ah0, bl, accK[0][j]);
      accK[1][j] = MFMA16(ah1, bl, accK[1][j]);
    }
  }

  // ---- epilogue: RoPE + scale + split, LDS-staged coalesced stores ----
  const int h = n0 >> 7;
#pragma unroll
  for (int i = 0; i < 2; i++) {
    const int grow0 = m0 + (2 * w + i) * 16;
    const int bb = grow0 >> 11, tt0 = grow0 & 2047;
    const size_t gbase = (((size_t)(bb * 16 + h)) * 2048 + tt0) * 128;

    // Q (escQ = sqrt(2048)*sqrt(128) = 512)
#pragma unroll
    for (int j = 0; j < 4; j++) {
      int d = j * 16 + l16;
      float s1 = sqk[h * 128 + d] * 512.0f;
      float s2 = sqk[h * 128 + d + 64] * 512.0f;
#pragma unroll
      for (int r = 0; r < 4; r++) {
        int t = tt0 + quad * 4 + r;
        float c = cosT[t * 64 + d], s = sinT[t * 64 + d];
        float xr = accQ[i][j][r], xi = accQ[i][j + 4][r];
        float o1 = (xr * c - xi * s) * s1;
        float o2 = (xr * s + xi * c) * s2;
        unsigned short h1 = f2bf(o1), h2 = f2bf(o2);
        int rl = quad * 4 + r;
        stage[w][0][rl * 136 + d] = h1;
        stage[w][0][rl * 136 + d + 64] = h2;
        stage[w][1][rl * 136 + d] = f2bf(o1 - bf2f(h1));
        stage[w][1][rl * 136 + d + 64] = f2bf(o2 - bf2f(h2));
      }
    }
#pragma unroll
    for (int it = 0; it < 4; it++) {
      int pb = it * 1024 + lane * 16;
      int rr = pb >> 8, cs = (pb & 255) >> 1;
      *(bf16x8*)(qhi + gbase + rr * 128 + cs) = ld8(&stage[w][0][rr * 136 + cs]);
      *(bf16x8*)(qlo + gbase + rr * 128 + cs) = ld8(&stage[w][1][rr * 136 + cs]);
    }

    // K (escK = sqrt(2048))
#pragma unroll
    for (int j = 0; j < 4; j++) {
      int d = j * 16 + l16;
      float s1 = sqk[h * 128 + d] * 45.254834f;
      float s2 = sqk[h * 128 + d + 64] * 45.254834f;
#pragma unroll
      for (int r = 0; r < 4; r++) {
        int t = tt0 + quad * 4 + r;
        float c = cosT[t * 64 + d], s = sinT[t * 64 + d];
        float xr = accK[i][j][r], xi = accK[i][j + 4][r];
        float o1 = (xr * c - xi * s) * s1;
        float o2 = (xr * s + xi * c) * s2;
        unsigned short h1 = f2bf(o1), h2 = f2bf(o2);
        int rl = quad * 4 + r;
        stage[w][0][rl * 136 + d] = h1;
        stage[w][0][rl * 136 + d + 64] = h2;
        stage[w][1][rl * 136 + d] = f2bf(o1 - bf2f(h1));
        stage[w][1][rl * 136 + d + 64] = f2bf(o2 - bf2f(h2));
      }
    }
#pragma unroll
    for (int it = 0; it < 4; it++) {
      int pb = it * 1024 + lane * 16;
      int rr = pb >> 8, cs = (pb & 255) >> 1;
      *(bf16x8*)(khi + gbase + rr * 128 + cs) = ld8(&stage[w][0][rr * 136 + cs]);
      *(bf16x8*)(klo + gbase + rr * 128 + cs) = ld8(&stage[w][1][rr * 136 + cs]);
    }
  }
}

// ---------------------------------------------------------------------------
// V projection, flatmm-style single pass (hi only), coalesced epilogue.
// out layout [B,NH,T,HD].
// ---------------------------------------------------------------------------
__global__ __launch_bounds__(256, 2) void gemm_v_flat(
    const unsigned short* __restrict__ xhi, const unsigned short* __restrict__ wvh,
    unsigned short* __restrict__ vout) {
  constexpr int Kd = 2048;
  int n0, m0;
  swizzle_nm(blockIdx.x, n0, m0);
  const int tid = threadIdx.x, w = tid >> 6, lane = tid & 63;
  const int quad = lane >> 4, l16 = lane & 15;

  __shared__ __align__(16) unsigned short stage[4][16 * 136];

  floatx4 acc[2][8];
#pragma unroll
  for (int i = 0; i < 2; i++)
#pragma unroll
    for (int j = 0; j < 8; j++) acc[i][j] = (floatx4){0.f, 0.f, 0.f, 0.f};

  const int t0 = 2 * w, t1 = 2 * w + 1;
  const size_t ra0 = (size_t)(m0 + t0 * 16 + l16) * Kd + quad * 8;
  const size_t ra1 = (size_t)(m0 + t1 * 16 + l16) * Kd + quad * 8;
  size_t rb[8];
#pragma unroll
  for (int j = 0; j < 8; j++)
    rb[j] = (size_t)(n0 + j * 16 + l16) * Kd + quad * 8;

  for (int k0 = 0; k0 < Kd; k0 += 32) {
    bf16x8 ah0 = ld8(xhi + ra0 + k0);
    bf16x8 ah1 = ld8(xhi + ra1 + k0);
#pragma unroll
    for (int j = 0; j < 8; j++) {
      bf16x8 b = ld8(wvh + rb[j] + k0);
      acc[0][j] = MFMA16(ah0, b, acc[0][j]);
      acc[1][j] = MFMA16(ah1, b, acc[1][j]);
    }
  }

  const int h = n0 >> 7;
#pragma unroll
  for (int i = 0; i < 2; i++) {
    const int grow0 = m0 + (2 * w + i) * 16;
    const int bb = grow0 >> 11, tt0 = grow0 & 2047;
    const size_t gbase = (((size_t)(bb * 16 + h)) * 2048 + tt0) * 128;
#pragma unroll
    for (int j = 0; j < 8; j++)
#pragma unroll
      for (int r = 0; r < 4; r++)
        stage[w][(quad * 4 + r) * 136 + j * 16 + l16] = f2bf(acc[i][j][r]);
#pragma unroll
    for (int it = 0; it < 4; it++) {
      int pb = it * 1024 + lane * 16;
      int rr = pb >> 8, cs = (pb & 255) >> 1;
      *(bf16x8*)(vout + gbase + rr * 128 + cs) = ld8(&stage[w][rr * 136 + cs]);
    }
  }
}

// ---------------------------------------------------------------------------
// O projection, flatmm-style: y = aout @ Wo^T, fp32 out (stores already
// 64 B/row-chunk coalesced).
// ---------------------------------------------------------------------------
__global__ __launch_bounds__(256, 2) void gemm_o_flat(
    const unsigned short* __restrict__ A, const unsigned short* __restrict__ B,
    float* __restrict__ outF) {
  constexpr int Kd = 2048;
  constexpr int Nd = 2048;
  int n0, m0;
  swizzle_nm(blockIdx.x, n0, m0);
  const int tid = threadIdx.x, w = tid >> 6, lane = tid & 63;
  const int quad = lane >> 4, l16 = lane & 15;

  floatx4 acc[2][8];
#pragma unroll
  for (int i = 0; i < 2; i++)
#pragma unroll
    for (int j = 0; j < 8; j++) acc[i][j] = (floatx4){0.f, 0.f, 0.f, 0.f};

  const int t0 = 2 * w, t1 = 2 * w + 1;
  const size_t ra0 = (size_t)(m0 + t0 * 16 + l16) * Kd + quad * 8;
  const size_t ra1 = (size_t)(m0 + t1 * 16 + l16) * Kd + quad * 8;
  size_t rb[8];
#pragma unroll
  for (int j = 0; j < 8; j++)
    rb[j] = (size_t)(n0 + j * 16 + l16) * Kd + quad * 8;

  for (int k0 = 0; k0 < Kd; k0 += 32) {
    bf16x8 a0 = ld8(A + ra0 + k0);
    bf16x8 a1 = ld8(A + ra1 + k0);
#pragma unroll
    for (int j = 0; j < 8; j++) {
      bf16x8 b = ld8(B + rb[j] + k0);
      acc[0][j] = MFMA16(a0, b, acc[0][j]);
      acc[1][j] = MFMA16(a1, b, acc[1][j]);
    }
  }

#pragma unroll
  for (int i = 0; i < 2; i++) {
    int rbase = m0 + (2 * w + i) * 16 + quad * 4;
#pragma unroll
    for (int j = 0; j < 8; j++) {
      int col = n0 + j * 16 + l16;
#pragma unroll
      for (int r = 0; r < 4; r++)
        outF[(size_t)(rbase + r) * Nd + col] = acc[i][j][r];
    }
  }
}

// ---------------------------------------------------------------------------
// transpose V: [BH][T][HD] -> [BH][HD][T] (bf16)
// ---------------------------------------------------------------------------
__global__ __launch_bounds__(256) void transpose_v(
    const unsigned short* __restrict__ v, unsigned short* __restrict__ vt) {
  __shared__ unsigned short tile[32][33];
  int t0 = blockIdx.x * 32, d0 = blockIdx.y * 32, bh = blockIdx.z;
  int tx = threadIdx.x & 31, ty = threadIdx.x >> 5;
  for (int r = ty; r < 32; r += 8)
    tile[r][tx] = v[((size_t)bh * 2048 + t0 + r) * 128 + d0 + tx];
  __syncthreads();
  for (int r = ty; r < 32; r += 8)
    vt[((size_t)bh * 128 + d0 + r) * 2048 + t0 + tx] = tile[tx][r];
}

// ---------------------------------------------------------------------------
// flash attention: block = (bh, q-tile of 128 rows). grid bh-major so each
// XCD holds 4 heads' K/V in L2. 4 waves x 32 rows, K-tiles of 64,
// QK^T 3-pass split-bf16, online softmax fp32, PV bf16.
// ---------------------------------------------------------------------------
__global__ __launch_bounds__(256, 2) void flash_attn(
    const unsigned short* __restrict__ qhi, const unsigned short* __restrict__ qlo,
    const unsigned short* __restrict__ khi, const unsigned short* __restrict__ klo,
    const unsigned short* __restrict__ vtp, unsigned short* __restrict__ aout) {
  constexpr int T = 2048, HD = 128;
  const int bh = blockIdx.x, qt = blockIdx.y;
  const int q0 = qt * 128;
  const int tid = threadIdx.x, w = tid >> 6, lane = tid & 63;
  const int quad = lane >> 4, l16 = lane & 15;

  __shared__ __align__(16) unsigned short Khi[8192];   // 64 x 128, granule layout
  __shared__ __align__(16) unsigned short Klo[8192];
  __shared__ __align__(16) unsigned short Vt[8192];    // 128 x 64, granule layout
  __shared__ __align__(16) unsigned short Pb[4][16 * 72];  // per-wave, padded

  const size_t qkbase = (size_t)bh * T * HD;

  bf16x8 qh[2][4], ql[2][4];
#pragma unroll
  for (int i = 0; i < 2; i++)
#pragma unroll
    for (int s = 0; s < 4; s++) {
      size_t off = qkbase + (size_t)(q0 + w * 32 + i * 16 + l16) * HD + s * 32 + quad * 8;
      qh[i][s] = *(const bf16x8*)(qhi + off);
      ql[i][s] = *(const bf16x8*)(qlo + off);
    }

  floatx4 o[2][8];
#pragma unroll
  for (int i = 0; i < 2; i++)
#pragma unroll
    for (int dt = 0; dt < 8; dt++) o[i][dt] = (floatx4){0.f, 0.f, 0.f, 0.f};
  float mrow[2][4], lrow[2][4];
#pragma unroll
  for (int i = 0; i < 2; i++)
#pragma unroll
    for (int r = 0; r < 4; r++) { mrow[i][r] = -3e38f; lrow[i][r] = 0.f; }

  const int ntiles = q0 / 64 + 2;
  for (int kt = 0; kt < ntiles; ++kt) {
    const int s0 = kt * 64;
    __syncthreads();
    for (int c = w; c < 16; c += 4) {
      int tt = c >> 2, ss = c & 3;
      size_t go = qkbase + (size_t)(s0 + tt * 16 + l16) * HD + ss * 32 + quad * 8;
      async16(&Khi[c * 512], khi + go);
      async16(&Klo[c * 512], klo + go);
      int dt = c >> 1, vs = c & 1;
      size_t vo = (size_t)bh * HD * T + (size_t)(dt * 16 + l16) * T + s0 + vs * 32 + quad * 8;
      async16(&Vt[c * 512], vtp + vo);
    }
    __syncthreads();

    floatx4 S[2][4];
#pragma unroll
    for (int i = 0; i < 2; i++)
#pragma unroll
      for (int j = 0; j < 4; j++) S[i][j] = (floatx4){0.f, 0.f, 0.f, 0.f};

#pragma unroll
    for (int s = 0; s < 4; s++) {
#pragma unroll
      for (int j = 0; j < 4; j++) {
        bf16x8 kh = ld8(&Khi[(j * 4 + s) * 512 + lane * 8]);
        bf16x8 kl = ld8(&Klo[(j * 4 + s) * 512 + lane * 8]);
        S[0][j] = MFMA16(qh[0][s], kh, S[0][j]);
        S[1][j] = MFMA16(qh[1][s], kh, S[1][j]);
        S[0][j] = MFMA16(ql[0][s], kh, S[0][j]);
        S[1][j] = MFMA16(ql[1][s], kh, S[1][j]);
        S[0][j] = MFMA16(qh[0][s], kl, S[0][j]);
        S[1][j] = MFMA16(qh[1][s], kl, S[1][j]);
      }
    }

    if (s0 + 63 > q0) {  // causal mask (only near-diagonal tiles)
#pragma unroll
      for (int i = 0; i < 2; i++) {
        int rb = q0 + w * 32 + i * 16 + quad * 4;
#pragma unroll
        for (int j = 0; j < 4; j++) {
          int cg = s0 + j * 16 + l16;
#pragma unroll
          for (int r = 0; r < 4; r++)
            if (cg > rb + r) S[i][j][r] = -3e38f;
        }
      }
    }

    bf16x8 pf[2][2];
#pragma unroll
    for (int i = 0; i < 2; i++) {
#pragma unroll
      for (int r = 0; r < 4; r++) {
        float mx = fmaxf(fmaxf(S[i][0][r], S[i][1][r]), fmaxf(S[i][2][r], S[i][3][r]));
#pragma unroll
        for (int d = 1; d < 16; d <<= 1) mx = fmaxf(mx, __shfl_xor(mx, d, 64));
        float mnew = fmaxf(mrow[i][r], mx);
        float al = __expf(mrow[i][r] - mnew);
        mrow[i][r] = mnew;
        float sum = 0.f;
#pragma unroll
        for (int j = 0; j < 4; j++) {
          float p = __expf(S[i][j][r] - mnew);
          S[i][j][r] = p;
          sum += p;
        }
#pragma unroll
        for (int d = 1; d < 16; d <<= 1) sum += __shfl_xor(sum, d, 64);
        lrow[i][r] = lrow[i][r] * al + sum;
#pragma unroll
        for (int dt = 0; dt < 8; dt++) o[i][dt][r] *= al;
      }
      // P -> LDS (A-fragment transform); per-wave buffer
#pragma unroll
      for (int r = 0; r < 4; r++)
#pragma unroll
        for (int j = 0; j < 4; j++)
          Pb[w][(quad * 4 + r) * 72 + j * 16 + l16] = f2bf(S[i][j][r]);
      pf[i][0] = ld8(&Pb[w][l16 * 72 + quad * 8]);
      pf[i][1] = ld8(&Pb[w][l16 * 72 + 32 + quad * 8]);
    }

#pragma unroll
    for (int dt = 0; dt < 8; dt++) {
#pragma unroll
      for (int s = 0; s < 2; s++) {
        bf16x8 vf = ld8(&Vt[(dt * 2 + s) * 512 + lane * 8]);
        o[0][dt] = MFMA16(pf[0][s], vf, o[0][dt]);
        o[1][dt] = MFMA16(pf[1][s], vf, o[1][dt]);
      }
    }
  }

  const int b = bh >> 4, h = bh & 15;
#pragma unroll
  for (int i = 0; i < 2; i++) {
#pragma unroll
    for (int r = 0; r < 4; r++) {
      int trow = q0 + w * 32 + i * 16 + quad * 4 + r;
      float linv = 1.0f / lrow[i][r];
      size_t base = ((size_t)(b * T + trow)) * 2048 + h * 128;
#pragma unroll
      for (int dt = 0; dt < 8; dt++)
        aout[base + dt * 16 + l16] = f2bf(o[i][dt][r] * linv);
    }
  }
}

// ---------------------------------------------------------------------------
// per-row L2 normalize: out = y / max(||y||, 1e-12)
// ---------------------------------------------------------------------------
__global__ __launch_bounds__(256) void rownorm(const float* __restrict__ y,
                                               float* __restrict__ out) {
  int row = blockIdx.x;
  const float4* yr = (const float4*)(y + (size_t)row * 2048);
  float4* od = (float4*)(out + (size_t)row * 2048);
  int t = threadIdx.x;
  float4 v0 = yr[t], v1 = yr[t + 256];
  float ss = v0.x * v0.x + v0.y * v0.y + v0.z * v0.z + v0.w * v0.w +
             v1.x * v1.x + v1.y * v1.y + v1.z * v1.z + v1.w * v1.w;
#pragma unroll
  for (int d = 1; d < 64; d <<= 1) ss += __shfl_xor(ss, d, 64);
  __shared__ float red[4];
  if ((t & 63) == 0) red[t >> 6] = ss;
  __syncthreads();
  float tot = red[0] + red[1] + red[2] + red[3];
  float inv = 1.0f / fmaxf(sqrtf(tot), 1e-12f);
  v0.x *= inv; v0.y *= inv; v0.z *= inv; v0.w *= inv;
  v1.x *= inv; v1.y *= inv; v1.z *= inv; v1.w *= inv;
  od[t] = v0;
  od[t + 256] = v1;
}

// ---------------------------------------------------------------------------
extern "C" void kernel_launch(void* const* d_in, const int* in_sizes, int n_in,
                              void* d_out, int out_size, void* d_ws, size_t ws_size,
                              hipStream_t stream) {
  (void)in_sizes; (void)n_in; (void)out_size; (void)ws_size;
  const float* x   = (const float*)d_in[0];
  const float* Wq  = (const float*)d_in[1];
  const float* Wk  = (const float*)d_in[2];
  const float* Wv  = (const float*)d_in[3];
  const float* Wo  = (const float*)d_in[4];
  const float* sqk = (const float*)d_in[5];
  char* ws = (char*)d_ws;

  constexpr size_t NX = 8388608;   // 2*2048*2048
  constexpr size_t NW = 4194304;   // 2048*2048
  constexpr size_t SZX = NX * 2;   // bf16 bytes
  constexpr size_t SZW = NW * 2;

  size_t o_xhi  = 0;
  size_t o_xlo  = o_xhi + SZX;
  size_t o_wqhi = o_xlo + SZX;
  size_t o_wqlo = o_wqhi + SZW;
  size_t o_wkhi = o_wqlo + SZW;
  size_t o_wklo = o_wkhi + SZW;
  size_t o_wvhi = o_wklo + SZW;
  size_t o_wohi = o_wvhi + SZW;
  size_t o_qhi  = o_wohi + SZW;
  size_t o_qlo  = o_qhi + SZX;
  size_t o_khi  = o_qlo + SZX;
  size_t o_klo  = o_khi + SZX;
  size_t o_v    = o_klo + SZX;
  size_t o_vt   = o_v + SZX;
  size_t o_cos  = o_vt + SZX;
  size_t o_sin  = o_cos + 2048 * 64 * 4;
  // aliases (lifetimes disjoint):
  size_t o_y    = o_xhi;   // fp32 y over x_hi+x_lo (x dead after projections)
  size_t o_aout = o_wqhi;  // attn-out over wq_hi+wq_lo (dead after projections)

  unsigned short* xhi  = (unsigned short*)(ws + o_xhi);
  unsigned short* xlo  = (unsigned short*)(ws + o_xlo);
  unsigned short* wqhi = (unsigned short*)(ws + o_wqhi);
  unsigned short* wqlo = (unsigned short*)(ws + o_wqlo);
  unsigned short* wkhi = (unsigned short*)(ws + o_wkhi);
  unsigned short* wklo = (unsigned short*)(ws + o_wklo);
  unsigned short* wvhi = (unsigned short*)(ws + o_wvhi);
  unsigned short* wohi = (unsigned short*)(ws + o_wohi);
  unsigned short* qhi  = (unsigned short*)(ws + o_qhi);
  unsigned short* qlo  = (unsigned short*)(ws + o_qlo);
  unsigned short* khi  = (unsigned short*)(ws + o_khi);
  unsigned short* klo  = (unsigned short*)(ws + o_klo);
  unsigned short* v    = (unsigned short*)(ws + o_v);
  unsigned short* vt   = (unsigned short*)(ws + o_vt);
  float* cosT = (float*)(ws + o_cos);
  float* sinT = (float*)(ws + o_sin);
  float* y    = (float*)(ws + o_y);
  unsigned short* aout = (unsigned short*)(ws + o_aout);

  // prep
  split_kernel<<<(int)(NX / 4 / 256), 256, 0, stream>>>((const float4*)x, (ushort4*)xhi, (ushort4*)xlo, (int)(NX / 4));
  split_kernel<<<(int)(NW / 4 / 256), 256, 0, stream>>>((const float4*)Wq, (ushort4*)wqhi, (ushort4*)wqlo, (int)(NW / 4));
  split_kernel<<<(int)(NW / 4 / 256), 256, 0, stream>>>((const float4*)Wk, (ushort4*)wkhi, (ushort4*)wklo, (int)(NW / 4));
  split_kernel<<<(int)(NW / 4 / 256), 256, 0, stream>>>((const float4*)Wv, (ushort4*)wvhi, (ushort4*)nullptr, (int)(NW / 4));
  split_kernel<<<(int)(NW / 4 / 256), 256, 0, stream>>>((const float4*)Wo, (ushort4*)wohi, (ushort4*)nullptr, (int)(NW / 4));
  rope_tables<<<512, 256, 0, stream>>>(cosT, sinT);

  // Projections: barrier-free flat GEMMs
  gemm_qk_flat<<<512, 256, 0, stream>>>(xhi, xlo, wqhi, wqlo, wkhi, wklo,
                                        cosT, sinT, sqk, qhi, qlo, khi, klo);
  gemm_v_flat<<<512, 256, 0, stream>>>(xhi, wvhi, v);
  transpose_v<<<dim3(64, 4, 32), 256, 0, stream>>>(v, vt);

  flash_attn<<<dim3(32, 16), 256, 0, stream>>>(qhi, qlo, khi, klo, vt, aout);

  // y = aout @ Wo^T (fp32 out)
  gemm_o_flat<<<512, 256, 0, stream>>>(aout, wohi, y);
  rownorm<<<4096, 256, 0, stream>>>(y, (float*)d_out);
}

// Round 5
// 557.884 us; speedup vs baseline: 2.1221x; 2.1221x over previous
//
#include <hip/hip_runtime.h>

#define DEVFN __device__ __forceinline__

typedef float    floatx4 __attribute__((ext_vector_type(4)));
typedef _Float16 half8   __attribute__((ext_vector_type(8)));
typedef _Float16 half4v  __attribute__((ext_vector_type(4)));

#define MFMA16H(a, b, c) __builtin_amdgcn_mfma_f32_16x16x32_f16((a), (b), (c), 0, 0, 0)

DEVFN void async16(void* lds, const void* g) {
  __builtin_amdgcn_global_load_lds(
      (const __attribute__((address_space(1))) unsigned int*)g,
      (__attribute__((address_space(3))) unsigned int*)lds, 16, 0, 0);
}
DEVFN half8 ld8h(const _Float16* p) { return *(const half8*)p; }

// ---------------------------------------------------------------------------
// prep: x -> fp16 hi/lo split; Wq,Wk,Wv,Wo -> fp16
// ---------------------------------------------------------------------------
__global__ __launch_bounds__(256) void cvt_prep(
    const float4* __restrict__ x, const float4* __restrict__ wq,
    const float4* __restrict__ wk, const float4* __restrict__ wv,
    const float4* __restrict__ wo,
    half4v* __restrict__ xh, half4v* __restrict__ xl,
    half4v* __restrict__ qo, half4v* __restrict__ ko,
    half4v* __restrict__ vo, half4v* __restrict__ oo) {
  int i = blockIdx.x * 256 + threadIdx.x;  // grid covers 2097152 float4 of x
  {
    float4 v = x[i];
    half4v h = {(_Float16)v.x, (_Float16)v.y, (_Float16)v.z, (_Float16)v.w};
    half4v l = {(_Float16)(v.x - (float)h.x), (_Float16)(v.y - (float)h.y),
                (_Float16)(v.z - (float)h.z), (_Float16)(v.w - (float)h.w)};
    xh[i] = h;
    xl[i] = l;
  }
  if (i < 1048576) {
    float4 v = wq[i];
    qo[i] = (half4v){(_Float16)v.x, (_Float16)v.y, (_Float16)v.z, (_Float16)v.w};
    v = wk[i];
    ko[i] = (half4v){(_Float16)v.x, (_Float16)v.y, (_Float16)v.z, (_Float16)v.w};
    v = wv[i];
    vo[i] = (half4v){(_Float16)v.x, (_Float16)v.y, (_Float16)v.z, (_Float16)v.w};
    v = wo[i];
    oo[i] = (half4v){(_Float16)v.x, (_Float16)v.y, (_Float16)v.z, (_Float16)v.w};
  }
}

// ---------------------------------------------------------------------------
// RoPE tables in fp64 (T=2048, d2=64)
// ---------------------------------------------------------------------------
__global__ __launch_bounds__(256) void rope_tables(float* __restrict__ cosT,
                                                   float* __restrict__ sinT) {
  int i = blockIdx.x * 256 + threadIdx.x;
  if (i >= 2048 * 64) return;
  int t = i >> 6, d = i & 63;
  double theta = exp(-((double)(2 * d) / 128.0) * log(10000.0));
  double ang = (double)t * theta;
  cosT[i] = (float)cos(ang);
  sinT[i] = (float)sin(ang);
}

// ---------------------------------------------------------------------------
// Fused QKV projection, fp16. 128x128 tile, BK=32, 5 staged LDS buffers
// (Xh, Xl, Wq, Wk, Wv = 40 KB). Q,K = 2-pass (x-split exact, W fp16-rounded),
// V = 1-pass. 80 MFMA/wave/k-step. Epilogue: RoPE fp32 -> split-fp16 q,k
// (hi+lo) + fp16 v at [B,NH,T,HD]; staged through the (now dead) K-loop LDS
// buffers so global stores are contiguous 16 B/lane.
// ---------------------------------------------------------------------------
__global__ __launch_bounds__(256, 2) void gemm_qkv_f16(
    const _Float16* __restrict__ xhp, const _Float16* __restrict__ xlp,
    const _Float16* __restrict__ wq, const _Float16* __restrict__ wk,
    const _Float16* __restrict__ wv,
    const float* __restrict__ cosT, const float* __restrict__ sinT,
    const float* __restrict__ sqk,
    _Float16* __restrict__ qhi, _Float16* __restrict__ qlo,
    _Float16* __restrict__ khi, _Float16* __restrict__ klo,
    _Float16* __restrict__ vo) {
  constexpr int Kd = 2048;
  const int n0 = blockIdx.x * 128, m0 = blockIdx.y * 128;
  const int tid = threadIdx.x, w = tid >> 6, lane = tid & 63;
  const int quad = lane >> 4, l16 = lane & 15;

  __shared__ __align__(16) _Float16 smem[5 * 4096];  // 40 KB
  _Float16* Xh = smem;
  _Float16* Xl = smem + 4096;
  _Float16* Qs = smem + 8192;
  _Float16* Ks = smem + 12288;
  _Float16* Vs = smem + 16384;
  // epilogue staging (aliased over K-loop buffers; used after final barrier)
  _Float16* stH = smem + w * 2176;         // 16 x 136 halves per wave
  _Float16* stL = smem + 8704 + w * 2176;

  floatx4 accQ[2][8], accK[2][8], accV[2][8];
#pragma unroll
  for (int i = 0; i < 2; i++)
#pragma unroll
    for (int j = 0; j < 8; j++) {
      accQ[i][j] = (floatx4){0.f, 0.f, 0.f, 0.f};
      accK[i][j] = (floatx4){0.f, 0.f, 0.f, 0.f};
      accV[i][j] = (floatx4){0.f, 0.f, 0.f, 0.f};
    }

  const int t0 = 2 * w, t1 = 2 * w + 1;
  const size_t xo0 = (size_t)(m0 + t0 * 16 + l16) * Kd + quad * 8;
  const size_t xo1 = (size_t)(m0 + t1 * 16 + l16) * Kd + quad * 8;
  const size_t wo0 = (size_t)(n0 + t0 * 16 + l16) * Kd + quad * 8;
  const size_t wo1 = (size_t)(n0 + t1 * 16 + l16) * Kd + quad * 8;

  for (int k0 = 0; k0 < Kd; k0 += 32) {
    __syncthreads();
    async16(&Xh[t0 * 512], xhp + xo0 + k0);
    async16(&Xh[t1 * 512], xhp + xo1 + k0);
    async16(&Xl[t0 * 512], xlp + xo0 + k0);
    async16(&Xl[t1 * 512], xlp + xo1 + k0);
    async16(&Qs[t0 * 512], wq + wo0 + k0);
    async16(&Qs[t1 * 512], wq + wo1 + k0);
    async16(&Ks[t0 * 512], wk + wo0 + k0);
    async16(&Ks[t1 * 512], wk + wo1 + k0);
    async16(&Vs[t0 * 512], wv + wo0 + k0);
    async16(&Vs[t1 * 512], wv + wo1 + k0);
    __syncthreads();
    half8 ah0 = ld8h(&Xh[t0 * 512 + lane * 8]);
    half8 ah1 = ld8h(&Xh[t1 * 512 + lane * 8]);
    half8 al0 = ld8h(&Xl[t0 * 512 + lane * 8]);
    half8 al1 = ld8h(&Xl[t1 * 512 + lane * 8]);
#pragma unroll
    for (int j = 0; j < 8; j++) {
      half8 b;
      b = ld8h(&Qs[j * 512 + lane * 8]);
      accQ[0][j] = MFMA16H(ah0, b, accQ[0][j]);
      accQ[1][j] = MFMA16H(ah1, b, accQ[1][j]);
      accQ[0][j] = MFMA16H(al0, b, accQ[0][j]);
      accQ[1][j] = MFMA16H(al1, b, accQ[1][j]);
      b = ld8h(&Ks[j * 512 + lane * 8]);
      accK[0][j] = MFMA16H(ah0, b, accK[0][j]);
      accK[1][j] = MFMA16H(ah1, b, accK[1][j]);
      accK[0][j] = MFMA16H(al0, b, accK[0][j]);
      accK[1][j] = MFMA16H(al1, b, accK[1][j]);
      b = ld8h(&Vs[j * 512 + lane * 8]);
      accV[0][j] = MFMA16H(ah0, b, accV[0][j]);
      accV[1][j] = MFMA16H(ah1, b, accV[1][j]);
    }
  }

  __syncthreads();  // K-loop LDS dead; safe to reuse as epilogue staging

  const int h = n0 >> 7;
#pragma unroll
  for (int i = 0; i < 2; i++) {
    const int grow0 = m0 + (2 * w + i) * 16;
    const int bb = grow0 >> 11, tt0 = grow0 & 2047;
    const size_t gbase = (((size_t)(bb * 16 + h)) * 2048 + tt0) * 128;

    // ---- Q: RoPE + sqk*sqrt(2048)*sqrt(128), split-fp16 ----
#pragma unroll
    for (int j = 0; j < 4; j++) {
      int d = j * 16 + l16;
      float s1 = sqk[h * 128 + d] * 512.0f;
      float s2 = sqk[h * 128 + d + 64] * 512.0f;
#pragma unroll
      for (int r = 0; r < 4; r++) {
        int t = tt0 + quad * 4 + r;
        float c = cosT[t * 64 + d], s = sinT[t * 64 + d];
        float xr = accQ[i][j][r], xi = accQ[i][j + 4][r];
        float o1 = (xr * c - xi * s) * s1;
        float o2 = (xr * s + xi * c) * s2;
        _Float16 h1 = (_Float16)o1, h2 = (_Float16)o2;
        int rl = quad * 4 + r;
        stH[rl * 136 + d] = h1;
        stH[rl * 136 + d + 64] = h2;
        stL[rl * 136 + d] = (_Float16)(o1 - (float)h1);
        stL[rl * 136 + d + 64] = (_Float16)(o2 - (float)h2);
      }
    }
#pragma unroll
    for (int it = 0; it < 4; it++) {
      int pb = it * 1024 + lane * 16;
      int rr = pb >> 8, cs = (pb & 255) >> 1;
      *(half8*)(qhi + gbase + rr * 128 + cs) = ld8h(&stH[rr * 136 + cs]);
      *(half8*)(qlo + gbase + rr * 128 + cs) = ld8h(&stL[rr * 136 + cs]);
    }

    // ---- K: RoPE + sqk*sqrt(2048), split-fp16 ----
#pragma unroll
    for (int j = 0; j < 4; j++) {
      int d = j * 16 + l16;
      float s1 = sqk[h * 128 + d] * 45.254834f;
      float s2 = sqk[h * 128 + d + 64] * 45.254834f;
#pragma unroll
      for (int r = 0; r < 4; r++) {
        int t = tt0 + quad * 4 + r;
        float c = cosT[t * 64 + d], s = sinT[t * 64 + d];
        float xr = accK[i][j][r], xi = accK[i][j + 4][r];
        float o1 = (xr * c - xi * s) * s1;
        float o2 = (xr * s + xi * c) * s2;
        _Float16 h1 = (_Float16)o1, h2 = (_Float16)o2;
        int rl = quad * 4 + r;
        stH[rl * 136 + d] = h1;
        stH[rl * 136 + d + 64] = h2;
        stL[rl * 136 + d] = (_Float16)(o1 - (float)h1);
        stL[rl * 136 + d + 64] = (_Float16)(o2 - (float)h2);
      }
    }
#pragma unroll
    for (int it = 0; it < 4; it++) {
      int pb = it * 1024 + lane * 16;
      int rr = pb >> 8, cs = (pb & 255) >> 1;
      *(half8*)(khi + gbase + rr * 128 + cs) = ld8h(&stH[rr * 136 + cs]);
      *(half8*)(klo + gbase + rr * 128 + cs) = ld8h(&stL[rr * 136 + cs]);
    }

    // ---- V: plain fp16 ----
#pragma unroll
    for (int j = 0; j < 8; j++)
#pragma unroll
      for (int r = 0; r < 4; r++)
        stH[(quad * 4 + r) * 136 + j * 16 + l16] = (_Float16)accV[i][j][r];
#pragma unroll
    for (int it = 0; it < 4; it++) {
      int pb = it * 1024 + lane * 16;
      int rr = pb >> 8, cs = (pb & 255) >> 1;
      *(half8*)(vo + gbase + rr * 128 + cs) = ld8h(&stH[rr * 136 + cs]);
    }
  }
}

// ---------------------------------------------------------------------------
// transpose V: [BH][T][HD] -> [BH][HD][T] (16-bit payload)
// ---------------------------------------------------------------------------
__global__ __launch_bounds__(256) void transpose_v(
    const unsigned short* __restrict__ v, unsigned short* __restrict__ vt) {
  __shared__ unsigned short tile[32][33];
  int t0 = blockIdx.x * 32, d0 = blockIdx.y * 32, bh = blockIdx.z;
  int tx = threadIdx.x & 31, ty = threadIdx.x >> 5;
  for (int r = ty; r < 32; r += 8)
    tile[r][tx] = v[((size_t)bh * 2048 + t0 + r) * 128 + d0 + tx];
  __syncthreads();
  for (int r = ty; r < 32; r += 8)
    vt[((size_t)bh * 128 + d0 + r) * 2048 + t0 + tx] = tile[tx][r];
}

// ---------------------------------------------------------------------------
// flash attention: block = (bh, 128 q-rows). 4 waves x 32 rows, K-tiles of
// 64. QK^T 3-pass split-fp16 (qh*kh + ql*kh + qh*kl), online softmax fp32,
// PV fp16. q,k split at [BH][T][128]; v transposed [BH][128][T].
// ---------------------------------------------------------------------------
__global__ __launch_bounds__(256, 2) void flash_attn(
    const _Float16* __restrict__ qhp, const _Float16* __restrict__ qlp,
    const _Float16* __restrict__ khp, const _Float16* __restrict__ klp,
    const _Float16* __restrict__ vtp, _Float16* __restrict__ aout) {
  constexpr int T = 2048, HD = 128;
  const int bh = blockIdx.x, qt = blockIdx.y;
  const int q0 = qt * 128;
  const int tid = threadIdx.x, w = tid >> 6, lane = tid & 63;
  const int quad = lane >> 4, l16 = lane & 15;

  __shared__ __align__(16) _Float16 Kh[8192];   // 64 x 128, granule layout
  __shared__ __align__(16) _Float16 Kl[8192];
  __shared__ __align__(16) _Float16 Vt[8192];   // 128 x 64, granule layout
  __shared__ __align__(16) _Float16 Pb[4][16 * 72];  // per-wave, padded

  const size_t qkbase = (size_t)bh * T * HD;

  half8 qh[2][4], ql[2][4];
#pragma unroll
  for (int i = 0; i < 2; i++)
#pragma unroll
    for (int s = 0; s < 4; s++) {
      size_t off = qkbase + (size_t)(q0 + w * 32 + i * 16 + l16) * HD + s * 32 + quad * 8;
      qh[i][s] = *(const half8*)(qhp + off);
      ql[i][s] = *(const half8*)(qlp + off);
    }

  floatx4 o[2][8];
#pragma unroll
  for (int i = 0; i < 2; i++)
#pragma unroll
    for (int dt = 0; dt < 8; dt++) o[i][dt] = (floatx4){0.f, 0.f, 0.f, 0.f};
  float mrow[2][4], lrow[2][4];
#pragma unroll
  for (int i = 0; i < 2; i++)
#pragma unroll
    for (int r = 0; r < 4; r++) { mrow[i][r] = -3e38f; lrow[i][r] = 0.f; }

  const int ntiles = q0 / 64 + 2;
  for (int kt = 0; kt < ntiles; ++kt) {
    const int s0 = kt * 64;
    __syncthreads();
    for (int c = w; c < 16; c += 4) {
      int tt = c >> 2, ss = c & 3;
      size_t go = qkbase + (size_t)(s0 + tt * 16 + l16) * HD + ss * 32 + quad * 8;
      async16(&Kh[c * 512], khp + go);
      async16(&Kl[c * 512], klp + go);
      int dt = c >> 1, vs = c & 1;
      size_t vo = (size_t)bh * HD * T + (size_t)(dt * 16 + l16) * T + s0 + vs * 32 + quad * 8;
      async16(&Vt[c * 512], vtp + vo);
    }
    __syncthreads();

    floatx4 S[2][4];
#pragma unroll
    for (int i = 0; i < 2; i++)
#pragma unroll
      for (int j = 0; j < 4; j++) S[i][j] = (floatx4){0.f, 0.f, 0.f, 0.f};

#pragma unroll
    for (int s = 0; s < 4; s++) {
#pragma unroll
      for (int j = 0; j < 4; j++) {
        half8 kh = ld8h(&Kh[(j * 4 + s) * 512 + lane * 8]);
        half8 kl = ld8h(&Kl[(j * 4 + s) * 512 + lane * 8]);
        S[0][j] = MFMA16H(qh[0][s], kh, S[0][j]);
        S[1][j] = MFMA16H(qh[1][s], kh, S[1][j]);
        S[0][j] = MFMA16H(ql[0][s], kh, S[0][j]);
        S[1][j] = MFMA16H(ql[1][s], kh, S[1][j]);
        S[0][j] = MFMA16H(qh[0][s], kl, S[0][j]);
        S[1][j] = MFMA16H(qh[1][s], kl, S[1][j]);
      }
    }

    if (s0 + 63 > q0) {  // causal mask (near-diagonal tiles only)
#pragma unroll
      for (int i = 0; i < 2; i++) {
        int rb = q0 + w * 32 + i * 16 + quad * 4;
#pragma unroll
        for (int j = 0; j < 4; j++) {
          int cg = s0 + j * 16 + l16;
#pragma unroll
          for (int r = 0; r < 4; r++)
            if (cg > rb + r) S[i][j][r] = -3e38f;
        }
      }
    }

    half8 pf[2][2];
#pragma unroll
    for (int i = 0; i < 2; i++) {
#pragma unroll
      for (int r = 0; r < 4; r++) {
        float mx = fmaxf(fmaxf(S[i][0][r], S[i][1][r]), fmaxf(S[i][2][r], S[i][3][r]));
#pragma unroll
        for (int d = 1; d < 16; d <<= 1) mx = fmaxf(mx, __shfl_xor(mx, d, 64));
        float mnew = fmaxf(mrow[i][r], mx);
        float al = __expf(mrow[i][r] - mnew);
        mrow[i][r] = mnew;
        float sum = 0.f;
#pragma unroll
        for (int j = 0; j < 4; j++) {
          float p = __expf(S[i][j][r] - mnew);
          S[i][j][r] = p;
          sum += p;
        }
#pragma unroll
        for (int d = 1; d < 16; d <<= 1) sum += __shfl_xor(sum, d, 64);
        lrow[i][r] = lrow[i][r] * al + sum;
#pragma unroll
        for (int dt = 0; dt < 8; dt++) o[i][dt][r] *= al;
      }
      // P -> LDS (A-fragment transform); per-wave buffer, DS in-order per wave
#pragma unroll
      for (int r = 0; r < 4; r++)
#pragma unroll
        for (int j = 0; j < 4; j++)
          Pb[w][(quad * 4 + r) * 72 + j * 16 + l16] = (_Float16)S[i][j][r];
      pf[i][0] = ld8h(&Pb[w][l16 * 72 + quad * 8]);
      pf[i][1] = ld8h(&Pb[w][l16 * 72 + 32 + quad * 8]);
    }

#pragma unroll
    for (int dt = 0; dt < 8; dt++) {
#pragma unroll
      for (int s = 0; s < 2; s++) {
        half8 vf = ld8h(&Vt[(dt * 2 + s) * 512 + lane * 8]);
        o[0][dt] = MFMA16H(pf[0][s], vf, o[0][dt]);
        o[1][dt] = MFMA16H(pf[1][s], vf, o[1][dt]);
      }
    }
  }

  const int b = bh >> 4, h = bh & 15;
#pragma unroll
  for (int i = 0; i < 2; i++) {
#pragma unroll
    for (int r = 0; r < 4; r++) {
      int trow = q0 + w * 32 + i * 16 + quad * 4 + r;
      float linv = 1.0f / lrow[i][r];
      size_t base = ((size_t)(b * T + trow)) * 2048 + h * 128;
#pragma unroll
      for (int dt = 0; dt < 8; dt++)
        aout[base + dt * 16 + l16] = (_Float16)(o[i][dt][r] * linv);
    }
  }
}

// ---------------------------------------------------------------------------
// O projection: y = aout @ Wo^T, fp16 in, fp32 out. 128x128 tile, BK=64.
// ---------------------------------------------------------------------------
__global__ __launch_bounds__(256, 2) void gemm_o_f16(
    const _Float16* __restrict__ A, const _Float16* __restrict__ B,
    float* __restrict__ outF) {
  constexpr int Kd = 2048;
  constexpr int Nd = 2048;
  const int n0 = blockIdx.x * 128, m0 = blockIdx.y * 128;
  const int tid = threadIdx.x, w = tid >> 6, lane = tid & 63;
  const int quad = lane >> 4, l16 = lane & 15;

  __shared__ __align__(16) _Float16 As[8192];  // two 32-k sub-tiles
  __shared__ __align__(16) _Float16 Bs[8192];

  floatx4 acc[2][8];
#pragma unroll
  for (int i = 0; i < 2; i++)
#pragma unroll
    for (int j = 0; j < 8; j++) acc[i][j] = (floatx4){0.f, 0.f, 0.f, 0.f};

  const int t0 = 2 * w, t1 = 2 * w + 1;
  const size_t ao0 = (size_t)(m0 + t0 * 16 + l16) * Kd + quad * 8;
  const size_t ao1 = (size_t)(m0 + t1 * 16 + l16) * Kd + quad * 8;
  const size_t bo0 = (size_t)(n0 + t0 * 16 + l16) * Kd + quad * 8;
  const size_t bo1 = (size_t)(n0 + t1 * 16 + l16) * Kd + quad * 8;

  for (int k0 = 0; k0 < Kd; k0 += 64) {
    __syncthreads();
    async16(&As[t0 * 512], A + ao0 + k0);
    async16(&As[t1 * 512], A + ao1 + k0);
    async16(&As[4096 + t0 * 512], A + ao0 + k0 + 32);
    async16(&As[4096 + t1 * 512], A + ao1 + k0 + 32);
    async16(&Bs[t0 * 512], B + bo0 + k0);
    async16(&Bs[t1 * 512], B + bo1 + k0);
    async16(&Bs[4096 + t0 * 512], B + bo0 + k0 + 32);
    async16(&Bs[4096 + t1 * 512], B + bo1 + k0 + 32);
    __syncthreads();
    half8 a00 = ld8h(&As[t0 * 512 + lane * 8]);
    half8 a10 = ld8h(&As[t1 * 512 + lane * 8]);
    half8 a01 = ld8h(&As[4096 + t0 * 512 + lane * 8]);
    half8 a11 = ld8h(&As[4096 + t1 * 512 + lane * 8]);
#pragma unroll
    for (int j = 0; j < 8; j++) {
      half8 b0 = ld8h(&Bs[j * 512 + lane * 8]);
      acc[0][j] = MFMA16H(a00, b0, acc[0][j]);
      acc[1][j] = MFMA16H(a10, b0, acc[1][j]);
      half8 b1 = ld8h(&Bs[4096 + j * 512 + lane * 8]);
      acc[0][j] = MFMA16H(a01, b1, acc[0][j]);
      acc[1][j] = MFMA16H(a11, b1, acc[1][j]);
    }
  }

#pragma unroll
  for (int i = 0; i < 2; i++) {
    int rbase = m0 + (2 * w + i) * 16 + quad * 4;
#pragma unroll
    for (int j = 0; j < 8; j++) {
      int col = n0 + j * 16 + l16;
#pragma unroll
      for (int r = 0; r < 4; r++)
        outF[(size_t)(rbase + r) * Nd + col] = acc[i][j][r];
    }
  }
}

// ---------------------------------------------------------------------------
// per-row L2 normalize: out = y / max(||y||, 1e-12)
// ---------------------------------------------------------------------------
__global__ __launch_bounds__(256) void rownorm(const float* __restrict__ y,
                                               float* __restrict__ out) {
  int row = blockIdx.x;
  const float4* yr = (const float4*)(y + (size_t)row * 2048);
  float4* od = (float4*)(out + (size_t)row * 2048);
  int t = threadIdx.x;
  float4 v0 = yr[t], v1 = yr[t + 256];
  float ss = v0.x * v0.x + v0.y * v0.y + v0.z * v0.z + v0.w * v0.w +
             v1.x * v1.x + v1.y * v1.y + v1.z * v1.z + v1.w * v1.w;
#pragma unroll
  for (int d = 1; d < 64; d <<= 1) ss += __shfl_xor(ss, d, 64);
  __shared__ float red[4];
  if ((t & 63) == 0) red[t >> 6] = ss;
  __syncthreads();
  float tot = red[0] + red[1] + red[2] + red[3];
  float inv = 1.0f / fmaxf(sqrtf(tot), 1e-12f);
  v0.x *= inv; v0.y *= inv; v0.z *= inv; v0.w *= inv;
  v1.x *= inv; v1.y *= inv; v1.z *= inv; v1.w *= inv;
  od[t] = v0;
  od[t + 256] = v1;
}

// ---------------------------------------------------------------------------
extern "C" void kernel_launch(void* const* d_in, const int* in_sizes, int n_in,
                              void* d_out, int out_size, void* d_ws, size_t ws_size,
                              hipStream_t stream) {
  (void)in_sizes; (void)n_in; (void)out_size; (void)ws_size;
  const float* x   = (const float*)d_in[0];
  const float* Wq  = (const float*)d_in[1];
  const float* Wk  = (const float*)d_in[2];
  const float* Wv  = (const float*)d_in[3];
  const float* Wo  = (const float*)d_in[4];
  const float* sqk = (const float*)d_in[5];
  char* ws = (char*)d_ws;

  constexpr size_t SZX = 8388608ull * 2;  // fp16 x-sized buffer (16 MB)
  constexpr size_t SZW = 4194304ull * 2;  // fp16 weight buffer (8 MB)

  size_t o_xh = 0;
  size_t o_xl = o_xh + SZX;
  size_t o_wq = o_xl + SZX;
  size_t o_wk = o_wq + SZW;
  size_t o_wv = o_wk + SZW;
  size_t o_wo = o_wv + SZW;
  size_t o_qh = o_wo + SZW;
  size_t o_ql = o_qh + SZX;
  size_t o_kh = o_ql + SZX;
  size_t o_kl = o_kh + SZX;
  size_t o_v  = o_kl + SZX;
  size_t o_vt = o_v + SZX;
  size_t o_cos = o_vt + SZX;
  size_t o_sin = o_cos + 2048 * 64 * 4;
  // aliases (lifetimes disjoint):
  size_t o_aout = o_wq;  // 16 MB over wq+wk (dead after QKV proj)
  size_t o_y    = o_qh;  // 32 MB fp32 over qh+ql (dead after flash)

  _Float16* xh = (_Float16*)(ws + o_xh);
  _Float16* xl = (_Float16*)(ws + o_xl);
  _Float16* wq = (_Float16*)(ws + o_wq);
  _Float16* wk = (_Float16*)(ws + o_wk);
  _Float16* wv = (_Float16*)(ws + o_wv);
  _Float16* wo = (_Float16*)(ws + o_wo);
  _Float16* qh = (_Float16*)(ws + o_qh);
  _Float16* ql = (_Float16*)(ws + o_ql);
  _Float16* kh = (_Float16*)(ws + o_kh);
  _Float16* kl = (_Float16*)(ws + o_kl);
  _Float16* v  = (_Float16*)(ws + o_v);
  _Float16* vt = (_Float16*)(ws + o_vt);
  float* cosT = (float*)(ws + o_cos);
  float* sinT = (float*)(ws + o_sin);
  _Float16* aout = (_Float16*)(ws + o_aout);
  float* y = (float*)(ws + o_y);

  cvt_prep<<<8192, 256, 0, stream>>>((const float4*)x, (const float4*)Wq,
                                     (const float4*)Wk, (const float4*)Wv,
                                     (const float4*)Wo, (half4v*)xh, (half4v*)xl,
                                     (half4v*)wq, (half4v*)wk, (half4v*)wv,
                                     (half4v*)wo);
  rope_tables<<<512, 256, 0, stream>>>(cosT, sinT);

  gemm_qkv_f16<<<dim3(16, 32), 256, 0, stream>>>(xh, xl, wq, wk, wv, cosT,
                                                 sinT, sqk, qh, ql, kh, kl, v);
  transpose_v<<<dim3(64, 4, 32), 256, 0, stream>>>((const unsigned short*)v,
                                                   (unsigned short*)vt);

  flash_attn<<<dim3(32, 16), 256, 0, stream>>>(qh, ql, kh, kl, vt, aout);

  gemm_o_f16<<<dim3(16, 32), 256, 0, stream>>>(aout, wo, y);
  rownorm<<<4096, 256, 0, stream>>>(y, (float*)d_out);
}

// Round 6
// 531.918 us; speedup vs baseline: 2.2257x; 1.0488x over previous
//
#include <hip/hip_runtime.h>

#define DEVFN __device__ __forceinline__

typedef float    floatx4 __attribute__((ext_vector_type(4)));
typedef _Float16 half8   __attribute__((ext_vector_type(8)));
typedef _Float16 half4v  __attribute__((ext_vector_type(4)));

#define MFMA16H(a, b, c) __builtin_amdgcn_mfma_f32_16x16x32_f16((a), (b), (c), 0, 0, 0)

DEVFN void async16(void* lds, const void* g) {
  __builtin_amdgcn_global_load_lds(
      (const __attribute__((address_space(1))) unsigned int*)g,
      (__attribute__((address_space(3))) unsigned int*)lds, 16, 0, 0);
}
DEVFN half8 ld8h(const _Float16* p) { return *(const half8*)p; }

// ---------------------------------------------------------------------------
// prep: x -> fp16 hi/lo split; Wq,Wk,Wv,Wo -> fp16; rope tables (fp64) folded
// ---------------------------------------------------------------------------
__global__ __launch_bounds__(256) void cvt_prep(
    const float4* __restrict__ x, const float4* __restrict__ wq,
    const float4* __restrict__ wk, const float4* __restrict__ wv,
    const float4* __restrict__ wo,
    half4v* __restrict__ xh, half4v* __restrict__ xl,
    half4v* __restrict__ qo, half4v* __restrict__ ko,
    half4v* __restrict__ vo, half4v* __restrict__ oo,
    float* __restrict__ cosT, float* __restrict__ sinT) {
  int i = blockIdx.x * 256 + threadIdx.x;  // grid covers 2097152 float4 of x
  {
    float4 v = x[i];
    half4v h = {(_Float16)v.x, (_Float16)v.y, (_Float16)v.z, (_Float16)v.w};
    half4v l = {(_Float16)(v.x - (float)h.x), (_Float16)(v.y - (float)h.y),
                (_Float16)(v.z - (float)h.z), (_Float16)(v.w - (float)h.w)};
    xh[i] = h;
    xl[i] = l;
  }
  if (i < 1048576) {
    float4 v = wq[i];
    qo[i] = (half4v){(_Float16)v.x, (_Float16)v.y, (_Float16)v.z, (_Float16)v.w};
    v = wk[i];
    ko[i] = (half4v){(_Float16)v.x, (_Float16)v.y, (_Float16)v.z, (_Float16)v.w};
    v = wv[i];
    vo[i] = (half4v){(_Float16)v.x, (_Float16)v.y, (_Float16)v.z, (_Float16)v.w};
    v = wo[i];
    oo[i] = (half4v){(_Float16)v.x, (_Float16)v.y, (_Float16)v.z, (_Float16)v.w};
  }
  if (i < 131072) {  // rope tables: t = i>>6, d = i&63
    int t = i >> 6, d = i & 63;
    double theta = exp(-((double)(2 * d) / 128.0) * log(10000.0));
    double ang = (double)t * theta;
    cosT[i] = (float)cos(ang);
    sinT[i] = (float)sin(ang);
  }
}

// ---------------------------------------------------------------------------
// Fused QKV projection, fp16. 128x128 tile, BK=32, 5 staged LDS buffers
// (Xh, Xl, Wq, Wk, Wv = 40 KB). Q,K = 2-pass (x-split exact, W fp16-rounded),
// V = 1-pass. 80 MFMA/wave/k-step. Epilogue: RoPE fp32; Q stored split-fp16
// (hi+lo), K and V stored single fp16, all at [B,NH,T,HD]; staged through
// the dead K-loop LDS so global stores are contiguous 16 B/lane.
// ---------------------------------------------------------------------------
__global__ __launch_bounds__(256, 2) void gemm_qkv_f16(
    const _Float16* __restrict__ xhp, const _Float16* __restrict__ xlp,
    const _Float16* __restrict__ wq, const _Float16* __restrict__ wk,
    const _Float16* __restrict__ wv,
    const float* __restrict__ cosT, const float* __restrict__ sinT,
    const float* __restrict__ sqk,
    _Float16* __restrict__ qhi, _Float16* __restrict__ qlo,
    _Float16* __restrict__ khi, _Float16* __restrict__ vo) {
  constexpr int Kd = 2048;
  const int n0 = blockIdx.x * 128, m0 = blockIdx.y * 128;
  const int tid = threadIdx.x, w = tid >> 6, lane = tid & 63;
  const int quad = lane >> 4, l16 = lane & 15;

  __shared__ __align__(16) _Float16 smem[5 * 4096];  // 40 KB
  _Float16* Xh = smem;
  _Float16* Xl = smem + 4096;
  _Float16* Qs = smem + 8192;
  _Float16* Ks = smem + 12288;
  _Float16* Vs = smem + 16384;
  // epilogue staging (aliased over K-loop buffers; used after final barrier)
  _Float16* stH = smem + w * 2176;         // 16 x 136 halves per wave
  _Float16* stL = smem + 8704 + w * 2176;

  floatx4 accQ[2][8], accK[2][8], accV[2][8];
#pragma unroll
  for (int i = 0; i < 2; i++)
#pragma unroll
    for (int j = 0; j < 8; j++) {
      accQ[i][j] = (floatx4){0.f, 0.f, 0.f, 0.f};
      accK[i][j] = (floatx4){0.f, 0.f, 0.f, 0.f};
      accV[i][j] = (floatx4){0.f, 0.f, 0.f, 0.f};
    }

  const int t0 = 2 * w, t1 = 2 * w + 1;
  const size_t xo0 = (size_t)(m0 + t0 * 16 + l16) * Kd + quad * 8;
  const size_t xo1 = (size_t)(m0 + t1 * 16 + l16) * Kd + quad * 8;
  const size_t wo0 = (size_t)(n0 + t0 * 16 + l16) * Kd + quad * 8;
  const size_t wo1 = (size_t)(n0 + t1 * 16 + l16) * Kd + quad * 8;

  for (int k0 = 0; k0 < Kd; k0 += 32) {
    __syncthreads();
    async16(&Xh[t0 * 512], xhp + xo0 + k0);
    async16(&Xh[t1 * 512], xhp + xo1 + k0);
    async16(&Xl[t0 * 512], xlp + xo0 + k0);
    async16(&Xl[t1 * 512], xlp + xo1 + k0);
    async16(&Qs[t0 * 512], wq + wo0 + k0);
    async16(&Qs[t1 * 512], wq + wo1 + k0);
    async16(&Ks[t0 * 512], wk + wo0 + k0);
    async16(&Ks[t1 * 512], wk + wo1 + k0);
    async16(&Vs[t0 * 512], wv + wo0 + k0);
    async16(&Vs[t1 * 512], wv + wo1 + k0);
    __syncthreads();
    half8 ah0 = ld8h(&Xh[t0 * 512 + lane * 8]);
    half8 ah1 = ld8h(&Xh[t1 * 512 + lane * 8]);
    half8 al0 = ld8h(&Xl[t0 * 512 + lane * 8]);
    half8 al1 = ld8h(&Xl[t1 * 512 + lane * 8]);
#pragma unroll
    for (int j = 0; j < 8; j++) {
      half8 b;
      b = ld8h(&Qs[j * 512 + lane * 8]);
      accQ[0][j] = MFMA16H(ah0, b, accQ[0][j]);
      accQ[1][j] = MFMA16H(ah1, b, accQ[1][j]);
      accQ[0][j] = MFMA16H(al0, b, accQ[0][j]);
      accQ[1][j] = MFMA16H(al1, b, accQ[1][j]);
      b = ld8h(&Ks[j * 512 + lane * 8]);
      accK[0][j] = MFMA16H(ah0, b, accK[0][j]);
      accK[1][j] = MFMA16H(ah1, b, accK[1][j]);
      accK[0][j] = MFMA16H(al0, b, accK[0][j]);
      accK[1][j] = MFMA16H(al1, b, accK[1][j]);
      b = ld8h(&Vs[j * 512 + lane * 8]);
      accV[0][j] = MFMA16H(ah0, b, accV[0][j]);
      accV[1][j] = MFMA16H(ah1, b, accV[1][j]);
    }
  }

  __syncthreads();  // K-loop LDS dead; safe to reuse as epilogue staging

  const int h = n0 >> 7;
#pragma unroll
  for (int i = 0; i < 2; i++) {
    const int grow0 = m0 + (2 * w + i) * 16;
    const int bb = grow0 >> 11, tt0 = grow0 & 2047;
    const size_t gbase = (((size_t)(bb * 16 + h)) * 2048 + tt0) * 128;

    // ---- Q: RoPE + sqk*sqrt(2048)*sqrt(128), split-fp16 ----
#pragma unroll
    for (int j = 0; j < 4; j++) {
      int d = j * 16 + l16;
      float s1 = sqk[h * 128 + d] * 512.0f;
      float s2 = sqk[h * 128 + d + 64] * 512.0f;
#pragma unroll
      for (int r = 0; r < 4; r++) {
        int t = tt0 + quad * 4 + r;
        float c = cosT[t * 64 + d], s = sinT[t * 64 + d];
        float xr = accQ[i][j][r], xi = accQ[i][j + 4][r];
        float o1 = (xr * c - xi * s) * s1;
        float o2 = (xr * s + xi * c) * s2;
        _Float16 h1 = (_Float16)o1, h2 = (_Float16)o2;
        int rl = quad * 4 + r;
        stH[rl * 136 + d] = h1;
        stH[rl * 136 + d + 64] = h2;
        stL[rl * 136 + d] = (_Float16)(o1 - (float)h1);
        stL[rl * 136 + d + 64] = (_Float16)(o2 - (float)h2);
      }
    }
#pragma unroll
    for (int it = 0; it < 4; it++) {
      int pb = it * 1024 + lane * 16;
      int rr = pb >> 8, cs = (pb & 255) >> 1;
      *(half8*)(qhi + gbase + rr * 128 + cs) = ld8h(&stH[rr * 136 + cs]);
      *(half8*)(qlo + gbase + rr * 128 + cs) = ld8h(&stL[rr * 136 + cs]);
    }

    // ---- K: RoPE + sqk*sqrt(2048), single fp16 ----
#pragma unroll
    for (int j = 0; j < 4; j++) {
      int d = j * 16 + l16;
      float s1 = sqk[h * 128 + d] * 45.254834f;
      float s2 = sqk[h * 128 + d + 64] * 45.254834f;
#pragma unroll
      for (int r = 0; r < 4; r++) {
        int t = tt0 + quad * 4 + r;
        float c = cosT[t * 64 + d], s = sinT[t * 64 + d];
        float xr = accK[i][j][r], xi = accK[i][j + 4][r];
        int rl = quad * 4 + r;
        stH[rl * 136 + d] = (_Float16)((xr * c - xi * s) * s1);
        stH[rl * 136 + d + 64] = (_Float16)((xr * s + xi * c) * s2);
      }
    }
#pragma unroll
    for (int it = 0; it < 4; it++) {
      int pb = it * 1024 + lane * 16;
      int rr = pb >> 8, cs = (pb & 255) >> 1;
      *(half8*)(khi + gbase + rr * 128 + cs) = ld8h(&stH[rr * 136 + cs]);
    }

    // ---- V: plain fp16 ----
#pragma unroll
    for (int j = 0; j < 8; j++)
#pragma unroll
      for (int r = 0; r < 4; r++)
        stH[(quad * 4 + r) * 136 + j * 16 + l16] = (_Float16)accV[i][j][r];
#pragma unroll
    for (int it = 0; it < 4; it++) {
      int pb = it * 1024 + lane * 16;
      int rr = pb >> 8, cs = (pb & 255) >> 1;
      *(half8*)(vo + gbase + rr * 128 + cs) = ld8h(&stH[rr * 136 + cs]);
    }
  }
}

// ---------------------------------------------------------------------------
// transpose V: [BH][T][HD] -> [BH][HD][T] (16-bit payload)
// ---------------------------------------------------------------------------
__global__ __launch_bounds__(256) void transpose_v(
    const unsigned short* __restrict__ v, unsigned short* __restrict__ vt) {
  __shared__ unsigned short tile[32][33];
  int t0 = blockIdx.x * 32, d0 = blockIdx.y * 32, bh = blockIdx.z;
  int tx = threadIdx.x & 31, ty = threadIdx.x >> 5;
  for (int r = ty; r < 32; r += 8)
    tile[r][tx] = v[((size_t)bh * 2048 + t0 + r) * 128 + d0 + tx];
  __syncthreads();
  for (int r = ty; r < 32; r += 8)
    vt[((size_t)bh * 128 + d0 + r) * 2048 + t0 + tx] = tile[tx][r];
}

// ---------------------------------------------------------------------------
// flash attention: block = (bh, 128 q-rows). 4 waves x 32 rows, K-tiles of
// 64. QK^T 2-pass (qh*kh + ql*kh; q split exact, k fp16-rounded), online
// softmax fp32, PV fp16. q split at [BH][T][128], k single fp16;
// v transposed [BH][128][T].
// ---------------------------------------------------------------------------
__global__ __launch_bounds__(256, 2) void flash_attn(
    const _Float16* __restrict__ qhp, const _Float16* __restrict__ qlp,
    const _Float16* __restrict__ khp,
    const _Float16* __restrict__ vtp, _Float16* __restrict__ aout) {
  constexpr int T = 2048, HD = 128;
  const int bh = blockIdx.x, qt = blockIdx.y;
  const int q0 = qt * 128;
  const int tid = threadIdx.x, w = tid >> 6, lane = tid & 63;
  const int quad = lane >> 4, l16 = lane & 15;

  __shared__ __align__(16) _Float16 Kh[8192];   // 64 x 128, granule layout
  __shared__ __align__(16) _Float16 Vt[8192];   // 128 x 64, granule layout
  __shared__ __align__(16) _Float16 Pb[4][16 * 72];  // per-wave, padded

  const size_t qkbase = (size_t)bh * T * HD;

  half8 qh[2][4], ql[2][4];
#pragma unroll
  for (int i = 0; i < 2; i++)
#pragma unroll
    for (int s = 0; s < 4; s++) {
      size_t off = qkbase + (size_t)(q0 + w * 32 + i * 16 + l16) * HD + s * 32 + quad * 8;
      qh[i][s] = *(const half8*)(qhp + off);
      ql[i][s] = *(const half8*)(qlp + off);
    }

  floatx4 o[2][8];
#pragma unroll
  for (int i = 0; i < 2; i++)
#pragma unroll
    for (int dt = 0; dt < 8; dt++) o[i][dt] = (floatx4){0.f, 0.f, 0.f, 0.f};
  float mrow[2][4], lrow[2][4];
#pragma unroll
  for (int i = 0; i < 2; i++)
#pragma unroll
    for (int r = 0; r < 4; r++) { mrow[i][r] = -3e38f; lrow[i][r] = 0.f; }

  const int ntiles = q0 / 64 + 2;
  for (int kt = 0; kt < ntiles; ++kt) {
    const int s0 = kt * 64;
    __syncthreads();
    for (int c = w; c < 16; c += 4) {
      int tt = c >> 2, ss = c & 3;
      size_t go = qkbase + (size_t)(s0 + tt * 16 + l16) * HD + ss * 32 + quad * 8;
      async16(&Kh[c * 512], khp + go);
      int dt = c >> 1, vs = c & 1;
      size_t vo = (size_t)bh * HD * T + (size_t)(dt * 16 + l16) * T + s0 + vs * 32 + quad * 8;
      async16(&Vt[c * 512], vtp + vo);
    }
    __syncthreads();

    floatx4 S[2][4];
#pragma unroll
    for (int i = 0; i < 2; i++)
#pragma unroll
      for (int j = 0; j < 4; j++) S[i][j] = (floatx4){0.f, 0.f, 0.f, 0.f};

#pragma unroll
    for (int s = 0; s < 4; s++) {
#pragma unroll
      for (int j = 0; j < 4; j++) {
        half8 kh = ld8h(&Kh[(j * 4 + s) * 512 + lane * 8]);
        S[0][j] = MFMA16H(qh[0][s], kh, S[0][j]);
        S[1][j] = MFMA16H(qh[1][s], kh, S[1][j]);
        S[0][j] = MFMA16H(ql[0][s], kh, S[0][j]);
        S[1][j] = MFMA16H(ql[1][s], kh, S[1][j]);
      }
    }

    if (s0 + 63 > q0) {  // causal mask (near-diagonal tiles only)
#pragma unroll
      for (int i = 0; i < 2; i++) {
        int rb = q0 + w * 32 + i * 16 + quad * 4;
#pragma unroll
        for (int j = 0; j < 4; j++) {
          int cg = s0 + j * 16 + l16;
#pragma unroll
          for (int r = 0; r < 4; r++)
            if (cg > rb + r) S[i][j][r] = -3e38f;
        }
      }
    }

    half8 pf[2][2];
#pragma unroll
    for (int i = 0; i < 2; i++) {
#pragma unroll
      for (int r = 0; r < 4; r++) {
        float mx = fmaxf(fmaxf(S[i][0][r], S[i][1][r]), fmaxf(S[i][2][r], S[i][3][r]));
#pragma unroll
        for (int d = 1; d < 16; d <<= 1) mx = fmaxf(mx, __shfl_xor(mx, d, 64));
        float mnew = fmaxf(mrow[i][r], mx);
        float al = __expf(mrow[i][r] - mnew);
        mrow[i][r] = mnew;
        float sum = 0.f;
#pragma unroll
        for (int j = 0; j < 4; j++) {
          float p = __expf(S[i][j][r] - mnew);
          S[i][j][r] = p;
          sum += p;
        }
#pragma unroll
        for (int d = 1; d < 16; d <<= 1) sum += __shfl_xor(sum, d, 64);
        lrow[i][r] = lrow[i][r] * al + sum;
#pragma unroll
        for (int dt = 0; dt < 8; dt++) o[i][dt][r] *= al;
      }
      // P -> LDS (A-fragment transform); per-wave buffer, DS in-order per wave
#pragma unroll
      for (int r = 0; r < 4; r++)
#pragma unroll
        for (int j = 0; j < 4; j++)
          Pb[w][(quad * 4 + r) * 72 + j * 16 + l16] = (_Float16)S[i][j][r];
      pf[i][0] = ld8h(&Pb[w][l16 * 72 + quad * 8]);
      pf[i][1] = ld8h(&Pb[w][l16 * 72 + 32 + quad * 8]);
    }

#pragma unroll
    for (int dt = 0; dt < 8; dt++) {
#pragma unroll
      for (int s = 0; s < 2; s++) {
        half8 vf = ld8h(&Vt[(dt * 2 + s) * 512 + lane * 8]);
        o[0][dt] = MFMA16H(pf[0][s], vf, o[0][dt]);
        o[1][dt] = MFMA16H(pf[1][s], vf, o[1][dt]);
      }
    }
  }

  const int b = bh >> 4, h = bh & 15;
#pragma unroll
  for (int i = 0; i < 2; i++) {
#pragma unroll
    for (int r = 0; r < 4; r++) {
      int trow = q0 + w * 32 + i * 16 + quad * 4 + r;
      float linv = 1.0f / lrow[i][r];
      size_t base = ((size_t)(b * T + trow)) * 2048 + h * 128;
#pragma unroll
      for (int dt = 0; dt < 8; dt++)
        aout[base + dt * 16 + l16] = (_Float16)(o[i][dt][r] * linv);
    }
  }
}

// ---------------------------------------------------------------------------
// O projection: y = aout @ Wo^T, fp16 in, fp32 out. 128x128 tile, BK=64.
// ---------------------------------------------------------------------------
__global__ __launch_bounds__(256, 2) void gemm_o_f16(
    const _Float16* __restrict__ A, const _Float16* __restrict__ B,
    float* __restrict__ outF) {
  constexpr int Kd = 2048;
  constexpr int Nd = 2048;
  const int n0 = blockIdx.x * 128, m0 = blockIdx.y * 128;
  const int tid = threadIdx.x, w = tid >> 6, lane = tid & 63;
  const int quad = lane >> 4, l16 = lane & 15;

  __shared__ __align__(16) _Float16 As[8192];  // two 32-k sub-tiles
  __shared__ __align__(16) _Float16 Bs[8192];

  floatx4 acc[2][8];
#pragma unroll
  for (int i = 0; i < 2; i++)
#pragma unroll
    for (int j = 0; j < 8; j++) acc[i][j] = (floatx4){0.f, 0.f, 0.f, 0.f};

  const int t0 = 2 * w, t1 = 2 * w + 1;
  const size_t ao0 = (size_t)(m0 + t0 * 16 + l16) * Kd + quad * 8;
  const size_t ao1 = (size_t)(m0 + t1 * 16 + l16) * Kd + quad * 8;
  const size_t bo0 = (size_t)(n0 + t0 * 16 + l16) * Kd + quad * 8;
  const size_t bo1 = (size_t)(n0 + t1 * 16 + l16) * Kd + quad * 8;

  for (int k0 = 0; k0 < Kd; k0 += 64) {
    __syncthreads();
    async16(&As[t0 * 512], A + ao0 + k0);
    async16(&As[t1 * 512], A + ao1 + k0);
    async16(&As[4096 + t0 * 512], A + ao0 + k0 + 32);
    async16(&As[4096 + t1 * 512], A + ao1 + k0 + 32);
    async16(&Bs[t0 * 512], B + bo0 + k0);
    async16(&Bs[t1 * 512], B + bo1 + k0);
    async16(&Bs[4096 + t0 * 512], B + bo0 + k0 + 32);
    async16(&Bs[4096 + t1 * 512], B + bo1 + k0 + 32);
    __syncthreads();
    half8 a00 = ld8h(&As[t0 * 512 + lane * 8]);
    half8 a10 = ld8h(&As[t1 * 512 + lane * 8]);
    half8 a01 = ld8h(&As[4096 + t0 * 512 + lane * 8]);
    half8 a11 = ld8h(&As[4096 + t1 * 512 + lane * 8]);
#pragma unroll
    for (int j = 0; j < 8; j++) {
      half8 b0 = ld8h(&Bs[j * 512 + lane * 8]);
      acc[0][j] = MFMA16H(a00, b0, acc[0][j]);
      acc[1][j] = MFMA16H(a10, b0, acc[1][j]);
      half8 b1 = ld8h(&Bs[4096 + j * 512 + lane * 8]);
      acc[0][j] = MFMA16H(a01, b1, acc[0][j]);
      acc[1][j] = MFMA16H(a11, b1, acc[1][j]);
    }
  }

#pragma unroll
  for (int i = 0; i < 2; i++) {
    int rbase = m0 + (2 * w + i) * 16 + quad * 4;
#pragma unroll
    for (int j = 0; j < 8; j++) {
      int col = n0 + j * 16 + l16;
#pragma unroll
      for (int r = 0; r < 4; r++)
        outF[(size_t)(rbase + r) * Nd + col] = acc[i][j][r];
    }
  }
}

// ---------------------------------------------------------------------------
// per-row L2 normalize: out = y / max(||y||, 1e-12)
// ---------------------------------------------------------------------------
__global__ __launch_bounds__(256) void rownorm(const float* __restrict__ y,
                                               float* __restrict__ out) {
  int row = blockIdx.x;
  const float4* yr = (const float4*)(y + (size_t)row * 2048);
  float4* od = (float4*)(out + (size_t)row * 2048);
  int t = threadIdx.x;
  float4 v0 = yr[t], v1 = yr[t + 256];
  float ss = v0.x * v0.x + v0.y * v0.y + v0.z * v0.z + v0.w * v0.w +
             v1.x * v1.x + v1.y * v1.y + v1.z * v1.z + v1.w * v1.w;
#pragma unroll
  for (int d = 1; d < 64; d <<= 1) ss += __shfl_xor(ss, d, 64);
  __shared__ float red[4];
  if ((t & 63) == 0) red[t >> 6] = ss;
  __syncthreads();
  float tot = red[0] + red[1] + red[2] + red[3];
  float inv = 1.0f / fmaxf(sqrtf(tot), 1e-12f);
  v0.x *= inv; v0.y *= inv; v0.z *= inv; v0.w *= inv;
  v1.x *= inv; v1.y *= inv; v1.z *= inv; v1.w *= inv;
  od[t] = v0;
  od[t + 256] = v1;
}

// ---------------------------------------------------------------------------
extern "C" void kernel_launch(void* const* d_in, const int* in_sizes, int n_in,
                              void* d_out, int out_size, void* d_ws, size_t ws_size,
                              hipStream_t stream) {
  (void)in_sizes; (void)n_in; (void)out_size; (void)ws_size;
  const float* x   = (const float*)d_in[0];
  const float* Wq  = (const float*)d_in[1];
  const float* Wk  = (const float*)d_in[2];
  const float* Wv  = (const float*)d_in[3];
  const float* Wo  = (const float*)d_in[4];
  const float* sqk = (const float*)d_in[5];
  char* ws = (char*)d_ws;

  constexpr size_t SZX = 8388608ull * 2;  // fp16 x-sized buffer (16 MB)
  constexpr size_t SZW = 4194304ull * 2;  // fp16 weight buffer (8 MB)

  size_t o_xh = 0;
  size_t o_xl = o_xh + SZX;
  size_t o_wq = o_xl + SZX;
  size_t o_wk = o_wq + SZW;
  size_t o_wv = o_wk + SZW;
  size_t o_wo = o_wv + SZW;
  size_t o_qh = o_wo + SZW;
  size_t o_ql = o_qh + SZX;
  size_t o_kh = o_ql + SZX;
  size_t o_v  = o_kh + SZX;
  size_t o_vt = o_v + SZX;
  size_t o_cos = o_vt + SZX;
  size_t o_sin = o_cos + 2048 * 64 * 4;
  // aliases (lifetimes disjoint):
  size_t o_aout = o_wq;  // 16 MB over wq+wk (dead after QKV proj)
  size_t o_y    = o_qh;  // 32 MB fp32 over qh+ql (dead after flash)

  _Float16* xh = (_Float16*)(ws + o_xh);
  _Float16* xl = (_Float16*)(ws + o_xl);
  _Float16* wq = (_Float16*)(ws + o_wq);
  _Float16* wk = (_Float16*)(ws + o_wk);
  _Float16* wv = (_Float16*)(ws + o_wv);
  _Float16* wo = (_Float16*)(ws + o_wo);
  _Float16* qh = (_Float16*)(ws + o_qh);
  _Float16* ql = (_Float16*)(ws + o_ql);
  _Float16* kh = (_Float16*)(ws + o_kh);
  _Float16* v  = (_Float16*)(ws + o_v);
  _Float16* vt = (_Float16*)(ws + o_vt);
  float* cosT = (float*)(ws + o_cos);
  float* sinT = (float*)(ws + o_sin);
  _Float16* aout = (_Float16*)(ws + o_aout);
  float* y = (float*)(ws + o_y);

  cvt_prep<<<8192, 256, 0, stream>>>((const float4*)x, (const float4*)Wq,
                                     (const float4*)Wk, (const float4*)Wv,
                                     (const float4*)Wo, (half4v*)xh, (half4v*)xl,
                                     (half4v*)wq, (half4v*)wk, (half4v*)wv,
                                     (half4v*)wo, cosT, sinT);

  gemm_qkv_f16<<<dim3(16, 32), 256, 0, stream>>>(xh, xl, wq, wk, wv, cosT,
                                                 sinT, sqk, qh, ql, kh, v);
  transpose_v<<<dim3(64, 4, 32), 256, 0, stream>>>((const unsigned short*)v,
                                                   (unsigned short*)vt);

  flash_attn<<<dim3(32, 16), 256, 0, stream>>>(qh, ql, kh, vt, aout);

  gemm_o_f16<<<dim3(16, 32), 256, 0, stream>>>(aout, wo, y);
  rownorm<<<4096, 256, 0, stream>>>(y, (float*)d_out);
}